// Round 1
// baseline (4130.650 us; speedup 1.0000x reference)
//
#include <hip/hip_runtime.h>
#include <math.h>

#define KD    1024   // k
#define BATCH 2048
#define XD    784
#define YD    10

#define TS  64
#define KS  32
#define LDP 68       // padded LDS stride (68*4 = 272 B = 17*16 -> float4 aligned)

// ---------------------------------------------------------------------------
// C[i][j] = sum_d A[d][i] * B[d][j]   (A: [K x M] row-major, B: [K x N] row-major)
// Used for WtW = Wx^T Wx and XtW = x^T Wx (both operands already k-major).
// ---------------------------------------------------------------------------
__global__ __launch_bounds__(256) void atb_kernel(const float* __restrict__ A,
                                                  const float* __restrict__ B,
                                                  float* __restrict__ C,
                                                  int M, int N, int K)
{
    __shared__ float As[KS][LDP];
    __shared__ float Bs[KS][LDP];
    const int tid = threadIdx.x;
    const int tx = tid & 15, ty = tid >> 4;
    const int i0 = blockIdx.y * TS, j0 = blockIdx.x * TS;
    float acc[4][4] = {};

    for (int k0 = 0; k0 < K; k0 += KS) {
#pragma unroll
        for (int q = 0; q < 2; ++q) {
            const int f  = tid + q * 256;           // 0..511
            const int kr = f >> 4;                  // 0..31
            const int cc = (f & 15) << 2;           // 0..60
            float4 av = make_float4(0.f, 0.f, 0.f, 0.f);
            float4 bv = av;
            if (k0 + kr < K) {
                av = *(const float4*)(A + (size_t)(k0 + kr) * M + i0 + cc);
                bv = *(const float4*)(B + (size_t)(k0 + kr) * N + j0 + cc);
            }
            *(float4*)&As[kr][cc] = av;
            *(float4*)&Bs[kr][cc] = bv;
        }
        __syncthreads();
#pragma unroll
        for (int kk = 0; kk < KS; ++kk) {
            const float4 a4 = *(const float4*)&As[kk][ty << 2];
            const float4 b4 = *(const float4*)&Bs[kk][tx << 2];
            const float a[4] = {a4.x, a4.y, a4.z, a4.w};
            const float b[4] = {b4.x, b4.y, b4.z, b4.w};
#pragma unroll
            for (int r = 0; r < 4; ++r)
#pragma unroll
                for (int c = 0; c < 4; ++c)
                    acc[r][c] = fmaf(a[r], b[c], acc[r][c]);
        }
        __syncthreads();
    }
#pragma unroll
    for (int r = 0; r < 4; ++r) {
        float4 o = make_float4(acc[r][0], acc[r][1], acc[r][2], acc[r][3]);
        *(float4*)(C + (size_t)(i0 + (ty << 2) + r) * N + j0 + (tx << 2)) = o;
    }
}

// ---------------------------------------------------------------------------
// Fused FISTA step:
//   grad  = Yin @ WtW - XtW
//   Hout  = max(Yin - grad*invL, 0)
//   Yout  = Hout + cm*(Hout - Hin)
// Yin: [BATCH x KD] row-major (GEMM A), WtW: [KD x KD] (GEMM B).
// ---------------------------------------------------------------------------
__global__ __launch_bounds__(256) void fista_kernel(const float* __restrict__ Yin,
                                                    const float* __restrict__ Hin,
                                                    const float* __restrict__ WtW,
                                                    const float* __restrict__ XtW,
                                                    const float* __restrict__ invLp,
                                                    float cm,
                                                    float* __restrict__ Hout,
                                                    float* __restrict__ Yout)
{
    __shared__ float As[KS][LDP];   // Y tile, stored k-major (transposed on stage)
    __shared__ float Bs[KS][LDP];   // WtW tile, naturally k-major
    const int tid = threadIdx.x;
    const int tx = tid & 15, ty = tid >> 4;
    const int i0 = blockIdx.y * TS, j0 = blockIdx.x * TS;
    float acc[4][4] = {};

    for (int k0 = 0; k0 < KD; k0 += KS) {
#pragma unroll
        for (int q = 0; q < 2; ++q) {
            const int f = tid + q * 256;            // 0..511
            // A: 64 rows x (KS/4 = 8) float4 along k, store transposed
            const int row = f >> 3;                 // 0..63
            const int c8  = (f & 7) << 2;           // 0..28
            const float4 av = *(const float4*)(Yin + (size_t)(i0 + row) * KD + k0 + c8);
            As[c8 + 0][row] = av.x;
            As[c8 + 1][row] = av.y;
            As[c8 + 2][row] = av.z;
            As[c8 + 3][row] = av.w;
            // B: 32 k-rows x 16 float4
            const int kr = f >> 4;                  // 0..31
            const int cc = (f & 15) << 2;           // 0..60
            const float4 bv = *(const float4*)(WtW + (size_t)(k0 + kr) * KD + j0 + cc);
            *(float4*)&Bs[kr][cc] = bv;
        }
        __syncthreads();
#pragma unroll
        for (int kk = 0; kk < KS; ++kk) {
            const float4 a4 = *(const float4*)&As[kk][ty << 2];
            const float4 b4 = *(const float4*)&Bs[kk][tx << 2];
            const float a[4] = {a4.x, a4.y, a4.z, a4.w};
            const float b[4] = {b4.x, b4.y, b4.z, b4.w};
#pragma unroll
            for (int r = 0; r < 4; ++r)
#pragma unroll
                for (int c = 0; c < 4; ++c)
                    acc[r][c] = fmaf(a[r], b[c], acc[r][c]);
        }
        __syncthreads();
    }

    const float invL = invLp[0];
#pragma unroll
    for (int r = 0; r < 4; ++r) {
        const size_t off = (size_t)(i0 + (ty << 2) + r) * KD + j0 + (tx << 2);
        const float4 xt = *(const float4*)(XtW + off);
        const float4 yv = *(const float4*)(Yin + off);
        const float4 hv = *(const float4*)(Hin + off);
        float4 hn, yn;
        hn.x = fmaxf(yv.x - (acc[r][0] - xt.x) * invL, 0.f);
        hn.y = fmaxf(yv.y - (acc[r][1] - xt.y) * invL, 0.f);
        hn.z = fmaxf(yv.z - (acc[r][2] - xt.z) * invL, 0.f);
        hn.w = fmaxf(yv.w - (acc[r][3] - xt.w) * invL, 0.f);
        yn.x = hn.x + cm * (hn.x - hv.x);
        yn.y = hn.y + cm * (hn.y - hv.y);
        yn.z = hn.z + cm * (hn.z - hv.z);
        yn.w = hn.w + cm * (hn.w - hv.w);
        *(float4*)(Hout + off) = hn;
        *(float4*)(Yout + off) = yn;
    }
}

// ---------------------------------------------------------------------------
// Power iteration pieces (all bitwise deterministic, no atomics)
// ---------------------------------------------------------------------------
__global__ void initv_kernel(float* __restrict__ v)
{
    v[threadIdx.x] = 0.03125f;   // 1/sqrt(1024), exact
}

// w = WtW @ v ; one wave per row, 4 rows per block
__global__ __launch_bounds__(256) void matvec_kernel(const float* __restrict__ WtW,
                                                     const float* __restrict__ v,
                                                     float* __restrict__ w)
{
    const int wave = threadIdx.x >> 6;
    const int lane = threadIdx.x & 63;
    const int row  = blockIdx.x * 4 + wave;
    const float* rp = WtW + (size_t)row * KD;
    float s = 0.f;
#pragma unroll
    for (int q = 0; q < KD / 64; ++q)
        s = fmaf(rp[lane + 64 * q], v[lane + 64 * q], s);
#pragma unroll
    for (int off = 32; off > 0; off >>= 1)
        s += __shfl_down(s, off);
    if (lane == 0) w[row] = s;
}

// v = w / (||w|| + 1e-12), single block of 1024 threads
__global__ __launch_bounds__(1024) void normscale_kernel(const float* __restrict__ w,
                                                         float* __restrict__ v)
{
    __shared__ float red[16];
    __shared__ float nrm;
    const int tid = threadIdx.x;
    const float x = w[tid];
    float s = x * x;
#pragma unroll
    for (int off = 32; off > 0; off >>= 1)
        s += __shfl_down(s, off);
    if ((tid & 63) == 0) red[tid >> 6] = s;
    __syncthreads();
    if (tid < 64) {                       // full wave active for shuffles
        float t = (tid < 16) ? red[tid] : 0.f;
#pragma unroll
        for (int off = 8; off > 0; off >>= 1)
            t += __shfl_down(t, off);
        if (tid == 0) nrm = sqrtf(t) + 1e-12f;
    }
    __syncthreads();
    v[tid] = x / nrm;
}

// invL = 1 / (v . w), single block of 1024 threads
__global__ __launch_bounds__(1024) void rayleigh_kernel(const float* __restrict__ v,
                                                        const float* __restrict__ w,
                                                        float* __restrict__ invL)
{
    __shared__ float red[16];
    const int tid = threadIdx.x;
    float s = v[tid] * w[tid];
#pragma unroll
    for (int off = 32; off > 0; off >>= 1)
        s += __shfl_down(s, off);
    if ((tid & 63) == 0) red[tid >> 6] = s;
    __syncthreads();
    if (tid < 64) {
        float t = (tid < 16) ? red[tid] : 0.f;
#pragma unroll
        for (int off = 8; off > 0; off >>= 1)
            t += __shfl_down(t, off);
        if (tid == 0) invL[0] = 1.0f / t;
    }
}

// ---------------------------------------------------------------------------
// out[i][b] = sum_j Wy[i][j] * H[b][j]   (out: [YD x BATCH])
// one wave per batch column b
// ---------------------------------------------------------------------------
__global__ __launch_bounds__(256) void ypred_kernel(const float* __restrict__ Wy,
                                                    const float* __restrict__ H,
                                                    float* __restrict__ out)
{
    const int wave = threadIdx.x >> 6;
    const int lane = threadIdx.x & 63;
    const int b    = blockIdx.x * 4 + wave;
    float p[YD] = {};
    const float* hp = H + (size_t)b * KD;
#pragma unroll 4
    for (int q = 0; q < KD / 64; ++q) {
        const int j = lane + 64 * q;
        const float hv = hp[j];
#pragma unroll
        for (int i = 0; i < YD; ++i)
            p[i] = fmaf(Wy[i * KD + j], hv, p[i]);
    }
#pragma unroll
    for (int i = 0; i < YD; ++i) {
        float s = p[i];
#pragma unroll
        for (int off = 32; off > 0; off >>= 1)
            s += __shfl_down(s, off);
        if (lane == 0) out[(size_t)i * BATCH + b] = s;
    }
}

// ---------------------------------------------------------------------------
extern "C" void kernel_launch(void* const* d_in, const int* in_sizes, int n_in,
                              void* d_out, int out_size, void* d_ws, size_t ws_size,
                              hipStream_t stream)
{
    const float* x      = (const float*)d_in[0];   // [784 x 2048]
    const float* Wx     = (const float*)d_in[1];   // [784 x 1024]
    const float* Wy     = (const float*)d_in[2];   // [10 x 1024]
    const float* h_init = (const float*)d_in[3];   // [2048 x 1024]
    float* out = (float*)d_out;                    // [10 x 2048]

    float* ws  = (float*)d_ws;
    float* WtW = ws;                               // 1024*1024
    float* XtW = WtW + (size_t)KD * KD;            // 2048*1024
    float* hA  = XtW + (size_t)BATCH * KD;
    float* hB  = hA  + (size_t)BATCH * KD;
    float* yA  = hB  + (size_t)BATCH * KD;
    float* yB  = yA  + (size_t)BATCH * KD;
    float* v   = yB  + (size_t)BATCH * KD;         // 1024
    float* w   = v + KD;                           // 1024
    float* invL = w + KD;                          // 1

    // 1) WtW = Wx^T Wx   (M=N=1024, K=784)
    atb_kernel<<<dim3(KD / TS, KD / TS), 256, 0, stream>>>(Wx, Wx, WtW, KD, KD, XD);
    // 2) XtW = x^T Wx    (M=2048, N=1024, K=784)
    atb_kernel<<<dim3(KD / TS, BATCH / TS), 256, 0, stream>>>(x, Wx, XtW, BATCH, KD, XD);

    // 3) Lipschitz via power iteration (30 iters), then Rayleigh quotient
    initv_kernel<<<1, 1024, 0, stream>>>(v);
    for (int it = 0; it < 30; ++it) {
        matvec_kernel<<<KD / 4, 256, 0, stream>>>(WtW, v, w);
        normscale_kernel<<<1, 1024, 0, stream>>>(w, v);
    }
    matvec_kernel<<<KD / 4, 256, 0, stream>>>(WtW, v, w);
    rayleigh_kernel<<<1, 1024, 0, stream>>>(v, w, invL);

    // 4) 60 FISTA iterations (t restarts at iter 50: phase-2 begins y = h, t = 1)
    const dim3 fgrid(KD / TS, BATCH / TS);
    float t = 1.0f;
    const float* hin = h_init;
    const float* yin = h_init;
    float* hout = hA;
    float* yout = yA;
    for (int n = 0; n < 60; ++n) {
        if (n == 50) { t = 1.0f; yin = hin; }
        const float tn = 0.5f * (1.0f + sqrtf(1.0f + 4.0f * t * t));
        const float cm = (t - 1.0f) / tn;
        fista_kernel<<<fgrid, 256, 0, stream>>>(yin, hin, WtW, XtW, invL, cm, hout, yout);
        t = tn;
        hin = hout;
        yin = yout;
        if (n & 1) { hout = hA; yout = yA; }
        else       { hout = hB; yout = yB; }
    }

    // 5) out = Wy @ h^T
    ypred_kernel<<<BATCH / 4, 256, 0, stream>>>(Wy, hin, out);
}

// Round 2
// 3027.370 us; speedup vs baseline: 1.3644x; 1.3644x over previous
//
#include <hip/hip_runtime.h>
#include <math.h>

#define KD    1024   // k
#define BATCH 2048
#define XD    784
#define YD    10

typedef _Float16 f16;
typedef _Float16 f16x8 __attribute__((ext_vector_type(8)));
typedef _Float16 f16x4 __attribute__((ext_vector_type(4)));
typedef float    f32x4 __attribute__((ext_vector_type(4)));

// ---------------------------------------------------------------------------
// C[i][j] = sum_d A[d][i] * B[d][j]   (A: [K x M] row-major, B: [K x N] row-major)
// fp32 setup GEMM (WtW = Wx^T Wx, XtW = x^T Wx).
// ---------------------------------------------------------------------------
#define TS  64
#define KS  32
#define LDP 68

__global__ __launch_bounds__(256) void atb_kernel(const float* __restrict__ A,
                                                  const float* __restrict__ B,
                                                  float* __restrict__ C,
                                                  int M, int N, int K)
{
    __shared__ float As[KS][LDP];
    __shared__ float Bs[KS][LDP];
    const int tid = threadIdx.x;
    const int tx = tid & 15, ty = tid >> 4;
    const int i0 = blockIdx.y * TS, j0 = blockIdx.x * TS;
    float acc[4][4] = {};

    for (int k0 = 0; k0 < K; k0 += KS) {
#pragma unroll
        for (int q = 0; q < 2; ++q) {
            const int f  = tid + q * 256;
            const int kr = f >> 4;
            const int cc = (f & 15) << 2;
            float4 av = make_float4(0.f, 0.f, 0.f, 0.f);
            float4 bv = av;
            if (k0 + kr < K) {
                av = *(const float4*)(A + (size_t)(k0 + kr) * M + i0 + cc);
                bv = *(const float4*)(B + (size_t)(k0 + kr) * N + j0 + cc);
            }
            *(float4*)&As[kr][cc] = av;
            *(float4*)&Bs[kr][cc] = bv;
        }
        __syncthreads();
#pragma unroll
        for (int kk = 0; kk < KS; ++kk) {
            const float4 a4 = *(const float4*)&As[kk][ty << 2];
            const float4 b4 = *(const float4*)&Bs[kk][tx << 2];
            const float a[4] = {a4.x, a4.y, a4.z, a4.w};
            const float b[4] = {b4.x, b4.y, b4.z, b4.w};
#pragma unroll
            for (int r = 0; r < 4; ++r)
#pragma unroll
                for (int c = 0; c < 4; ++c)
                    acc[r][c] = fmaf(a[r], b[c], acc[r][c]);
        }
        __syncthreads();
    }
#pragma unroll
    for (int r = 0; r < 4; ++r) {
        float4 o = make_float4(acc[r][0], acc[r][1], acc[r][2], acc[r][3]);
        *(float4*)(C + (size_t)(i0 + (ty << 2) + r) * N + j0 + (tx << 2)) = o;
    }
}

// ---------------------------------------------------------------------------
// Elementwise fp32 -> f16 hi/lo split (optionally scaled).
// ---------------------------------------------------------------------------
__global__ __launch_bounds__(256) void split_kernel(const float* __restrict__ src,
                                                    f16* __restrict__ hi,
                                                    f16* __restrict__ lo,
                                                    float scale, int n4)
{
    const int i = blockIdx.x * 256 + threadIdx.x;
    if (i >= n4) return;
    const float4 v = ((const float4*)src)[i];
    const float a0 = v.x * scale, a1 = v.y * scale, a2 = v.z * scale, a3 = v.w * scale;
    const f16 h0 = (f16)a0, h1 = (f16)a1, h2 = (f16)a2, h3 = (f16)a3;
    const f16 l0 = (f16)(a0 - (float)h0);
    const f16 l1 = (f16)(a1 - (float)h1);
    const f16 l2 = (f16)(a2 - (float)h2);
    const f16 l3 = (f16)(a3 - (float)h3);
    f16x4 hv = {h0, h1, h2, h3};
    f16x4 lv = {l0, l1, l2, l3};
    ((f16x4*)hi)[i] = hv;
    ((f16x4*)lo)[i] = lv;
}

// ---------------------------------------------------------------------------
// Fused FISTA step via split-f16 MFMA:
//   acc = Yin @ (256*WtW)  (3 MFMA: hi*hi + hi*lo + lo*hi, fp32 accumulate)
//   grad = acc/256 - XtW ; Hout = max(Yin - grad*invL, 0); Yout = Hout + cm*(Hout-Hin)
// Y/H stored as f16 hi/lo plane pairs [BATCH][KD]; WtW planes [KD][KD] (symmetric).
// Block: 256 thr (4 waves 2x2), tile BM=128 x BN=64, BK=64, wave-tile 64x32,
// MFMA 16x16x32_f16. LDS is fragment-chunk-major: every ds_read/ds_write_b128
// by a wave touches a contiguous 1 KiB block (conflict-free by construction).
// ---------------------------------------------------------------------------
#define BM 128
#define BN 64
#define BK 64

__global__ __launch_bounds__(256) void fista_mfma(
    const f16* __restrict__ yhiP, const f16* __restrict__ yloP,
    const f16* __restrict__ hhiP, const f16* __restrict__ hloP,
    const f16* __restrict__ bhiP, const f16* __restrict__ bloP,
    const float* __restrict__ xtw,
    const float* __restrict__ invLp, float cm,
    f16* __restrict__ HhiO, f16* __restrict__ HloO,
    f16* __restrict__ YhiO, f16* __restrict__ YloO)
{
    __shared__ float4 lds4[3072];            // 48 KiB
    char* ldsc = (char*)lds4;
    const int AH = 0, AL = 16384, BH = 32768, BL = 40960;

    const int t    = threadIdx.x;
    const int lane = t & 63;
    const int wid  = t >> 6;
    const int wm   = wid >> 1, wn = wid & 1;
    const int m0   = blockIdx.y * BM, n0 = blockIdx.x * BN;

    // Staging chunk decode. A chunks: c=(s*8+g)*64+l -> row=16g+(l&15), k=32s+8*(l>>4)
    size_t aSrc[4]; int aLds[4];
#pragma unroll
    for (int p = 0; p < 4; ++p) {
        const int c = t + 256 * p;
        const int l = c & 63, g = (c >> 6) & 7, s = c >> 9;
        const int row = 16 * g + (l & 15);
        const int kk  = 32 * s + 8 * (l >> 4);
        aSrc[p] = (size_t)(m0 + row) * KD + kk;
        aLds[p] = 16 * c;
    }
    size_t bSrc[2]; int bLds[2];
#pragma unroll
    for (int p = 0; p < 2; ++p) {
        const int c = t + 256 * p;
        const int l = c & 63, g = (c >> 6) & 3, s = c >> 8;
        const int col = 16 * g + (l & 15);
        const int kk  = 32 * s + 8 * (l >> 4);
        bSrc[p] = (size_t)(n0 + col) * KD + kk;
        bLds[p] = 16 * c;
    }

    f32x4 acc[4][2];
#pragma unroll
    for (int f = 0; f < 4; ++f)
#pragma unroll
        for (int b = 0; b < 2; ++b)
            acc[f][b] = (f32x4){0.f, 0.f, 0.f, 0.f};

    // preload k-tile 0 into registers
    f16x8 sAh[4], sAl[4], sBh[2], sBl[2];
#pragma unroll
    for (int p = 0; p < 4; ++p) {
        sAh[p] = *(const f16x8*)(yhiP + aSrc[p]);
        sAl[p] = *(const f16x8*)(yloP + aSrc[p]);
    }
#pragma unroll
    for (int p = 0; p < 2; ++p) {
        sBh[p] = *(const f16x8*)(bhiP + bSrc[p]);
        sBl[p] = *(const f16x8*)(bloP + bSrc[p]);
    }

    for (int kt = 0; kt < KD / BK; ++kt) {
        if (kt) __syncthreads();             // previous tile's reads done
#pragma unroll
        for (int p = 0; p < 4; ++p) {
            *(f16x8*)(ldsc + AH + aLds[p]) = sAh[p];
            *(f16x8*)(ldsc + AL + aLds[p]) = sAl[p];
        }
#pragma unroll
        for (int p = 0; p < 2; ++p) {
            *(f16x8*)(ldsc + BH + bLds[p]) = sBh[p];
            *(f16x8*)(ldsc + BL + bLds[p]) = sBl[p];
        }
        __syncthreads();

        if (kt + 1 < KD / BK) {              // prefetch next tile (overlaps MFMA)
            const int ko = (kt + 1) * BK;
#pragma unroll
            for (int p = 0; p < 4; ++p) {
                sAh[p] = *(const f16x8*)(yhiP + aSrc[p] + ko);
                sAl[p] = *(const f16x8*)(yloP + aSrc[p] + ko);
            }
#pragma unroll
            for (int p = 0; p < 2; ++p) {
                sBh[p] = *(const f16x8*)(bhiP + bSrc[p] + ko);
                sBl[p] = *(const f16x8*)(bloP + bSrc[p] + ko);
            }
        }

        // fragment reads for both k-steps (contiguous 1 KiB per wave read)
        f16x8 Ah[2][4], Al[2][4], Bh[2][2], Bl[2][2];
#pragma unroll
        for (int s = 0; s < 2; ++s) {
#pragma unroll
            for (int f = 0; f < 4; ++f) {
                const int off = ((s * 8 + wm * 4 + f) << 10) + (lane << 4);
                Ah[s][f] = *(const f16x8*)(ldsc + AH + off);
                Al[s][f] = *(const f16x8*)(ldsc + AL + off);
            }
#pragma unroll
            for (int b = 0; b < 2; ++b) {
                const int off = ((s * 4 + wn * 2 + b) << 10) + (lane << 4);
                Bh[s][b] = *(const f16x8*)(ldsc + BH + off);
                Bl[s][b] = *(const f16x8*)(ldsc + BL + off);
            }
        }
        // 3-pass split MFMA: independent (f,b) back-to-back to hide dep latency
#pragma unroll
        for (int s = 0; s < 2; ++s) {
#pragma unroll
            for (int f = 0; f < 4; ++f)
#pragma unroll
                for (int b = 0; b < 2; ++b)
                    acc[f][b] = __builtin_amdgcn_mfma_f32_16x16x32_f16(Al[s][f], Bh[s][b], acc[f][b], 0, 0, 0);
#pragma unroll
            for (int f = 0; f < 4; ++f)
#pragma unroll
                for (int b = 0; b < 2; ++b)
                    acc[f][b] = __builtin_amdgcn_mfma_f32_16x16x32_f16(Ah[s][f], Bl[s][b], acc[f][b], 0, 0, 0);
#pragma unroll
            for (int f = 0; f < 4; ++f)
#pragma unroll
                for (int b = 0; b < 2; ++b)
                    acc[f][b] = __builtin_amdgcn_mfma_f32_16x16x32_f16(Ah[s][f], Bh[s][b], acc[f][b], 0, 0, 0);
        }
    }

    // ---- epilogue: acc -> LDS (padded) -> linear, vectorized global I/O ----
    __syncthreads();
    float* eb = (float*)lds4;                // [128][68] fp32, 34.8 KiB
#pragma unroll
    for (int f = 0; f < 4; ++f)
#pragma unroll
        for (int b = 0; b < 2; ++b) {
            const int row0 = wm * 64 + 16 * f + 4 * (lane >> 4);
            const int col  = wn * 32 + 16 * b + (lane & 15);
#pragma unroll
            for (int r = 0; r < 4; ++r)
                eb[(row0 + r) * 68 + col] = acc[f][b][r];
        }
    __syncthreads();

    const int row = t >> 1;
    const int cb  = (t & 1) * 32;
    const float invL  = invLp[0];
    const float invLs = invL * 0.00390625f;  // invL/256 (fold WtW scale)
    const size_t gb = (size_t)(m0 + row) * KD + n0 + cb;
#pragma unroll
    for (int q = 0; q < 4; ++q) {            // 8 elements per chunk
        const f32x4 a0 = *(const f32x4*)(eb + row * 68 + cb + q * 8);
        const f32x4 a1 = *(const f32x4*)(eb + row * 68 + cb + q * 8 + 4);
        const size_t g8 = gb + q * 8;
        const f16x8 yh8 = *(const f16x8*)(yhiP + g8);
        const f16x8 yl8 = *(const f16x8*)(yloP + g8);
        const f16x8 hh8 = *(const f16x8*)(hhiP + g8);
        const f16x8 hl8 = *(const f16x8*)(hloP + g8);
        const f32x4 xt0 = *(const f32x4*)(xtw + g8);
        const f32x4 xt1 = *(const f32x4*)(xtw + g8 + 4);
        f16x8 ohh, ohl, oyh, oyl;
#pragma unroll
        for (int j = 0; j < 8; ++j) {
            const float av = (j < 4) ? a0[j] : a1[j - 4];
            const float xv = (j < 4) ? xt0[j] : xt1[j - 4];
            const float yv = (float)yh8[j] + (float)yl8[j];
            const float hv = (float)hh8[j] + (float)hl8[j];
            const float t1 = fmaf(invL, xv, yv);
            const float hn = fmaxf(fmaf(-invLs, av, t1), 0.f);
            const float yn = fmaf(cm, hn - hv, hn);
            const f16 hh = (f16)hn; const f16 hl = (f16)(hn - (float)hh);
            const f16 yh = (f16)yn; const f16 yl = (f16)(yn - (float)yh);
            ohh[j] = hh; ohl[j] = hl; oyh[j] = yh; oyl[j] = yl;
        }
        *(f16x8*)(HhiO + g8) = ohh;
        *(f16x8*)(HloO + g8) = ohl;
        *(f16x8*)(YhiO + g8) = oyh;
        *(f16x8*)(YloO + g8) = oyl;
    }
}

// ---------------------------------------------------------------------------
// Power iteration: wout = WtW @ (win / (||win||+1e-12)); norm computed
// redundantly per block (deterministic, no cross-block communication).
// ---------------------------------------------------------------------------
__global__ void initw_kernel(float* __restrict__ w)
{
    w[threadIdx.x] = 0.03125f;               // 1/sqrt(1024), ||w||=1 exactly
}

__global__ __launch_bounds__(256) void matvec_n_kernel(const float* __restrict__ WtW,
                                                       const float* __restrict__ win,
                                                       float* __restrict__ wout)
{
    __shared__ float red[4];
    __shared__ float invnS;
    const int t = threadIdx.x;
    const int wave = t >> 6, lane = t & 63;

    const float4 wv = *(const float4*)(win + t * 4);
    float ss = wv.x * wv.x + wv.y * wv.y + wv.z * wv.z + wv.w * wv.w;
#pragma unroll
    for (int off = 32; off > 0; off >>= 1) ss += __shfl_down(ss, off);
    if (lane == 0) red[wave] = ss;
    __syncthreads();
    if (t == 0) invnS = 1.0f / (sqrtf(red[0] + red[1] + red[2] + red[3]) + 1e-12f);
    __syncthreads();
    const float invn = invnS;

    const int row = blockIdx.x * 4 + wave;
    const float* rp = WtW + (size_t)row * KD;
    float s = 0.f;
#pragma unroll
    for (int q = 0; q < KD / 64; ++q)
        s = fmaf(rp[lane + 64 * q], win[lane + 64 * q] * invn, s);
#pragma unroll
    for (int off = 32; off > 0; off >>= 1) s += __shfl_down(s, off);
    if (lane == 0) wout[row] = s;
}

// invL = 1 / ( (w30/||w30||) . u31 )
__global__ __launch_bounds__(1024) void rayleigh_n_kernel(const float* __restrict__ w30,
                                                          const float* __restrict__ u31,
                                                          float* __restrict__ invL)
{
    __shared__ float red[16];
    __shared__ float invnS;
    const int t = threadIdx.x;
    const float a = w30[t];
    float ss = a * a;
#pragma unroll
    for (int off = 32; off > 0; off >>= 1) ss += __shfl_down(ss, off);
    if ((t & 63) == 0) red[t >> 6] = ss;
    __syncthreads();
    if (t < 64) {
        float v = (t < 16) ? red[t] : 0.f;
#pragma unroll
        for (int off = 8; off > 0; off >>= 1) v += __shfl_down(v, off);
        if (t == 0) invnS = 1.0f / (sqrtf(v) + 1e-12f);
    }
    __syncthreads();
    float s = (a * invnS) * u31[t];
#pragma unroll
    for (int off = 32; off > 0; off >>= 1) s += __shfl_down(s, off);
    __syncthreads();
    if ((t & 63) == 0) red[t >> 6] = s;
    __syncthreads();
    if (t == 0) {
        float tot = 0.f;
#pragma unroll
        for (int i = 0; i < 16; ++i) tot += red[i];
        invL[0] = 1.0f / tot;
    }
}

// ---------------------------------------------------------------------------
// out[i][b] = sum_j Wy[i][j] * (Hhi[b][j]+Hlo[b][j])   (out: [YD x BATCH])
// ---------------------------------------------------------------------------
__global__ __launch_bounds__(256) void ypred_kernel(const float* __restrict__ Wy,
                                                    const f16* __restrict__ hhi,
                                                    const f16* __restrict__ hlo,
                                                    float* __restrict__ out)
{
    const int wave = threadIdx.x >> 6;
    const int lane = threadIdx.x & 63;
    const int b    = blockIdx.x * 4 + wave;
    float p[YD] = {};
    const f16* h1 = hhi + (size_t)b * KD;
    const f16* h2 = hlo + (size_t)b * KD;
#pragma unroll 4
    for (int q = 0; q < KD / 64; ++q) {
        const int j = lane + 64 * q;
        const float hv = (float)h1[j] + (float)h2[j];
#pragma unroll
        for (int i = 0; i < YD; ++i)
            p[i] = fmaf(Wy[i * KD + j], hv, p[i]);
    }
#pragma unroll
    for (int i = 0; i < YD; ++i) {
        float s = p[i];
#pragma unroll
        for (int off = 32; off > 0; off >>= 1)
            s += __shfl_down(s, off);
        if (lane == 0) out[(size_t)i * BATCH + b] = s;
    }
}

// ---------------------------------------------------------------------------
extern "C" void kernel_launch(void* const* d_in, const int* in_sizes, int n_in,
                              void* d_out, int out_size, void* d_ws, size_t ws_size,
                              hipStream_t stream)
{
    const float* x      = (const float*)d_in[0];   // [784 x 2048]
    const float* Wx     = (const float*)d_in[1];   // [784 x 1024]
    const float* Wy     = (const float*)d_in[2];   // [10 x 1024]
    const float* h_init = (const float*)d_in[3];   // [2048 x 1024]
    float* out = (float*)d_out;                    // [10 x 2048]

    char* base = (char*)d_ws;
    const size_t MB = 1 << 20;
    float* WtW  = (float*)(base + 0 * MB);         // 4 MB
    float* XtW  = (float*)(base + 4 * MB);         // 8 MB
    f16* bhiP   = (f16*)(base + 12 * MB);          // 2 MB
    f16* bloP   = (f16*)(base + 14 * MB);          // 2 MB
    f16* s1hh   = (f16*)(base + 16 * MB);
    f16* s1hl   = (f16*)(base + 20 * MB);
    f16* s1yh   = (f16*)(base + 24 * MB);
    f16* s1yl   = (f16*)(base + 28 * MB);
    f16* s2hh   = (f16*)(base + 32 * MB);
    f16* s2hl   = (f16*)(base + 36 * MB);
    f16* s2yh   = (f16*)(base + 40 * MB);
    f16* s2yl   = (f16*)(base + 44 * MB);
    float* wA   = (float*)(base + 48 * MB);
    float* wB   = (float*)(base + 48 * MB + 8192);
    float* invL = (float*)(base + 48 * MB + 16384);

    // 1) WtW = Wx^T Wx ; XtW = x^T Wx
    atb_kernel<<<dim3(KD / TS, KD / TS), 256, 0, stream>>>(Wx, Wx, WtW, KD, KD, XD);
    atb_kernel<<<dim3(KD / TS, BATCH / TS), 256, 0, stream>>>(x, Wx, XtW, BATCH, KD, XD);

    // 2) split WtW (scaled x256) and h_init into f16 hi/lo planes
    split_kernel<<<(KD * KD / 4 + 255) / 256, 256, 0, stream>>>(WtW, bhiP, bloP, 256.0f, KD * KD / 4);
    split_kernel<<<(BATCH * KD / 4 + 255) / 256, 256, 0, stream>>>(h_init, s2hh, s2hl, 1.0f, BATCH * KD / 4);

    // 3) Lipschitz: 31 fused norm+matvec launches, then Rayleigh
    initw_kernel<<<1, 1024, 0, stream>>>(wA);
    float* wcur = wA; float* wnxt = wB;
    for (int it = 0; it < 31; ++it) {
        matvec_n_kernel<<<KD / 4, 256, 0, stream>>>(WtW, wcur, wnxt);
        float* tmp = wcur; wcur = wnxt; wnxt = tmp;
    }
    // after 31 launches: u30 in wnxt's... u30 = result of launch 30 -> in buffer written at it=29? Track:
    // launches write: it=0 -> wB(u1), it=1 -> wA(u2), ..., it=29 -> wB(u30), it=30 -> wA(u31).
    // So w30 = wB, u31 = wA.
    rayleigh_n_kernel<<<1, 1024, 0, stream>>>(wB, wA, invL);

    // 4) 60 FISTA iterations (t restarts at iter 50: y = h, t = 1)
    float t = 1.0f;
    const f16 *yin_h = s2hh, *yin_l = s2hl, *hin_h = s2hh, *hin_l = s2hl;
    int outSel = 1;                                 // 1 -> S1, 0 -> S2
    for (int n = 0; n < 60; ++n) {
        if (n == 50) { t = 1.0f; yin_h = hin_h; yin_l = hin_l; }
        const float tn = 0.5f * (1.0f + sqrtf(1.0f + 4.0f * t * t));
        const float cm = (t - 1.0f) / tn;
        f16 *oh_h = outSel ? s1hh : s2hh;
        f16 *oh_l = outSel ? s1hl : s2hl;
        f16 *oy_h = outSel ? s1yh : s2yh;
        f16 *oy_l = outSel ? s1yl : s2yl;
        fista_mfma<<<dim3(KD / BN, BATCH / BM), 256, 0, stream>>>(
            yin_h, yin_l, hin_h, hin_l, bhiP, bloP, XtW, invL, cm,
            oh_h, oh_l, oy_h, oy_l);
        t = tn;
        hin_h = oh_h; hin_l = oh_l; yin_h = oy_h; yin_l = oy_l;
        outSel ^= 1;
    }

    // 5) out = Wy @ h^T
    ypred_kernel<<<BATCH / 4, 256, 0, stream>>>(Wy, hin_h, hin_l, out);
}

// Round 3
// 2041.909 us; speedup vs baseline: 2.0229x; 1.4826x over previous
//
#include <hip/hip_runtime.h>
#include <math.h>

#define KD    1024   // k
#define BATCH 2048
#define XD    784
#define YD    10

typedef _Float16 f16;
typedef _Float16 f16x8 __attribute__((ext_vector_type(8)));
typedef _Float16 f16x4 __attribute__((ext_vector_type(4)));
typedef float    f32x4 __attribute__((ext_vector_type(4)));

// ---------------------------------------------------------------------------
// C[i][j] = sum_d A[d][i] * B[d][j]   (A: [K x M], B: [K x N], both k-major)
// fp32 setup GEMM (WtW = Wx^T Wx, XtW = x^T Wx).
// ---------------------------------------------------------------------------
#define TS  64
#define KS  32
#define LDP 68

__global__ __launch_bounds__(256) void atb_kernel(const float* __restrict__ A,
                                                  const float* __restrict__ B,
                                                  float* __restrict__ C,
                                                  int M, int N, int K)
{
    __shared__ float As[KS][LDP];
    __shared__ float Bs[KS][LDP];
    const int tid = threadIdx.x;
    const int tx = tid & 15, ty = tid >> 4;
    const int i0 = blockIdx.y * TS, j0 = blockIdx.x * TS;
    float acc[4][4] = {};

    for (int k0 = 0; k0 < K; k0 += KS) {
#pragma unroll
        for (int q = 0; q < 2; ++q) {
            const int f  = tid + q * 256;
            const int kr = f >> 4;
            const int cc = (f & 15) << 2;
            float4 av = make_float4(0.f, 0.f, 0.f, 0.f);
            float4 bv = av;
            if (k0 + kr < K) {
                av = *(const float4*)(A + (size_t)(k0 + kr) * M + i0 + cc);
                bv = *(const float4*)(B + (size_t)(k0 + kr) * N + j0 + cc);
            }
            *(float4*)&As[kr][cc] = av;
            *(float4*)&Bs[kr][cc] = bv;
        }
        __syncthreads();
#pragma unroll
        for (int kk = 0; kk < KS; ++kk) {
            const float4 a4 = *(const float4*)&As[kk][ty << 2];
            const float4 b4 = *(const float4*)&Bs[kk][tx << 2];
            const float a[4] = {a4.x, a4.y, a4.z, a4.w};
            const float b[4] = {b4.x, b4.y, b4.z, b4.w};
#pragma unroll
            for (int r = 0; r < 4; ++r)
#pragma unroll
                for (int c = 0; c < 4; ++c)
                    acc[r][c] = fmaf(a[r], b[c], acc[r][c]);
        }
        __syncthreads();
    }
#pragma unroll
    for (int r = 0; r < 4; ++r) {
        float4 o = make_float4(acc[r][0], acc[r][1], acc[r][2], acc[r][3]);
        *(float4*)(C + (size_t)(i0 + (ty << 2) + r) * N + j0 + (tx << 2)) = o;
    }
}

// ---------------------------------------------------------------------------
// fp32 -> f16 hi/lo split (scaled). Used for B = 256*WtW.
// ---------------------------------------------------------------------------
__global__ __launch_bounds__(256) void split_kernel(const float* __restrict__ src,
                                                    f16* __restrict__ hi,
                                                    f16* __restrict__ lo,
                                                    float scale, int n4)
{
    const int i = blockIdx.x * 256 + threadIdx.x;
    if (i >= n4) return;
    const float4 v = ((const float4*)src)[i];
    const float a0 = v.x * scale, a1 = v.y * scale, a2 = v.z * scale, a3 = v.w * scale;
    const f16 h0 = (f16)a0, h1 = (f16)a1, h2 = (f16)a2, h3 = (f16)a3;
    const f16 l0 = (f16)(a0 - (float)h0);
    const f16 l1 = (f16)(a1 - (float)h1);
    const f16 l2 = (f16)(a2 - (float)h2);
    const f16 l3 = (f16)(a3 - (float)h3);
    f16x4 hv = {h0, h1, h2, h3};
    f16x4 lv = {l0, l1, l2, l3};
    ((f16x4*)hi)[i] = hv;
    ((f16x4*)lo)[i] = lv;
}

// fp32 -> f16 (round), vectorized x8
__global__ __launch_bounds__(256) void tof16_kernel(const float* __restrict__ src,
                                                    f16* __restrict__ dst, int n8)
{
    const int i = blockIdx.x * 256 + threadIdx.x;
    if (i >= n8) return;
    const f32x4 a = ((const f32x4*)src)[2 * i];
    const f32x4 b = ((const f32x4*)src)[2 * i + 1];
    f16x8 o;
#pragma unroll
    for (int j = 0; j < 4; ++j) { o[j] = (f16)a[j]; o[j + 4] = (f16)b[j]; }
    ((f16x8*)dst)[i] = o;
}

// ---------------------------------------------------------------------------
// Fused FISTA step, 2-pass split-f16 MFMA:
//   acc = Y @ (256*WtW)  via  Yh*Bh + Yh*Bl   (fp32 accumulate)
//   grad = acc/256 - XtW ; Hout = max(Y - grad*invL, 0); Yout = Hout + cm*(Hout-Hin)
// Y,H stored as single f16 planes (iterate f16-rounding is benign; B hi+lo keeps
// the W-rounding bias out). A (=Y) fragments are loaded DIRECT from global,
// double-buffered one k-tile deep in registers. Only B lives in LDS: two 32 KiB
// halves, each covering 2 k-tiles (k-range 128), staged load-early/write-late.
// Block: 256 thr = 4 waves (2m x 2n), wave-tile 64x32, BM=128, BN=64, grid 16x16.
// ---------------------------------------------------------------------------
#define BMF 128
#define BNF 64

__global__ __launch_bounds__(256, 1) void fista2(
    const f16* __restrict__ yhP,   // A operand + epilogue y  [BATCH][KD]
    const f16* __restrict__ hhP,   // epilogue h              [BATCH][KD]
    const f16* __restrict__ bhiP,  // 256*WtW hi plane        [KD][KD]
    const f16* __restrict__ bloP,  // 256*WtW lo plane
    const float* __restrict__ xtw, // fp32 [BATCH][KD]
    const float* __restrict__ invLp, float cm,
    f16* __restrict__ HO, f16* __restrict__ YO)
{
    __shared__ char lds[65536];            // 2 halves x 32 KiB (B only)
    const int t    = threadIdx.x;
    const int lane = t & 63;
    const int wid  = t >> 6;
    const int wm   = wid >> 1, wn = wid & 1;
    const int m0   = blockIdx.y * BMF, n0 = blockIdx.x * BNF;

    f32x4 acc[4][2] = {};

    // per-lane A row base (element index), k-lane part folded in
    size_t aRow[4];
#pragma unroll
    for (int f = 0; f < 4; ++f)
        aRow[f] = (size_t)(m0 + wm * 64 + f * 16 + (lane & 15)) * KD + 8 * (lane >> 4);

    // --- B staging: chunk c in 0..31 per half; this thread stages c = wid*8+i.
    //     g=c&3 (col grp), p=(c>>2)&1 (plane), kk=c>>3 (32-k step within half)
    //     src: col = n0+16g+(lane&15), k = kh + kk*32 + 8*(lane>>4)
    //     lds: half*32768 + c*1024 + lane*16
    f16x8 sb[8];
    auto stage_load = [&](int kh) {
#pragma unroll
        for (int i = 0; i < 8; ++i) {
            const int c = wid * 8 + i;
            const int g = c & 3, p = (c >> 2) & 1, kk = c >> 3;
            const f16* pl = p ? bloP : bhiP;
            sb[i] = *(const f16x8*)(pl + (size_t)(n0 + 16 * g + (lane & 15)) * KD
                                       + kh + kk * 32 + 8 * (lane >> 4));
        }
    };
    auto stage_write = [&](int half) {
#pragma unroll
        for (int i = 0; i < 8; ++i) {
            const int c = wid * 8 + i;
            *(f16x8*)(lds + half * 32768 + c * 1024 + lane * 16) = sb[i];
        }
    };

    f16x8 A0[2][4], A1[2][4];
    auto loadA = [&](f16x8 (&dst)[2][4], int kt) {
#pragma unroll
        for (int s = 0; s < 2; ++s)
#pragma unroll
            for (int f = 0; f < 4; ++f)
                dst[s][f] = *(const f16x8*)(yhP + aRow[f] + kt * 64 + s * 32);
    };

    auto compute_ktile = [&](int kt, f16x8 (&Acur)[2][4], f16x8 (&Anext)[2][4]) {
        const int half = (kt >> 1) & 1;
        if (kt < 15) loadA(Anext, kt + 1);
#pragma unroll
        for (int s = 0; s < 2; ++s) {
            f16x8 Bh[2], Bl[2];
#pragma unroll
            for (int b = 0; b < 2; ++b) {
                const int kk = (kt & 1) * 2 + s;
                Bh[b] = *(const f16x8*)(lds + half * 32768 + ((kk * 2 + 0) * 4 + (wn * 2 + b)) * 1024 + lane * 16);
                Bl[b] = *(const f16x8*)(lds + half * 32768 + ((kk * 2 + 1) * 4 + (wn * 2 + b)) * 1024 + lane * 16);
            }
#pragma unroll
            for (int f = 0; f < 4; ++f)
#pragma unroll
                for (int b = 0; b < 2; ++b)
                    acc[f][b] = __builtin_amdgcn_mfma_f32_16x16x32_f16(Acur[s][f], Bh[b], acc[f][b], 0, 0, 0);
#pragma unroll
            for (int f = 0; f < 4; ++f)
#pragma unroll
                for (int b = 0; b < 2; ++b)
                    acc[f][b] = __builtin_amdgcn_mfma_f32_16x16x32_f16(Acur[s][f], Bl[b], acc[f][b], 0, 0, 0);
        }
    };

    // prologue: stage half0 (k 0..127), preload A k-tile 0
    stage_load(0);
    loadA(A0, 0);
    stage_write(0);
    __syncthreads();

    for (int g = 0; g < 8; ++g) {          // group = 2 k-tiles = 128 k
        if (g < 7) stage_load((g + 1) * 128);
        compute_ktile(2 * g,     A0, A1);
        compute_ktile(2 * g + 1, A1, A0);
        if (g < 7) stage_write((g + 1) & 1);
        __syncthreads();
    }

    // ---- epilogue: acc -> LDS fp32 [128][68] -> linear global I/O ----
    float* eb = (float*)lds;
#pragma unroll
    for (int f = 0; f < 4; ++f)
#pragma unroll
        for (int b = 0; b < 2; ++b) {
            const int row0 = wm * 64 + 16 * f + 4 * (lane >> 4);
            const int col  = wn * 32 + 16 * b + (lane & 15);
#pragma unroll
            for (int r = 0; r < 4; ++r)
                eb[(row0 + r) * 68 + col] = acc[f][b][r];
        }
    __syncthreads();

    const int row = t >> 1;
    const int cb  = (t & 1) * 32;
    const float invL  = invLp[0];
    const float invLs = invL * 0.00390625f;   // invL/256 (fold WtW scale)
    const size_t gb = (size_t)(m0 + row) * KD + n0 + cb;
#pragma unroll
    for (int q = 0; q < 4; ++q) {
        const f32x4 a0 = *(const f32x4*)(eb + row * 68 + cb + q * 8);
        const f32x4 a1 = *(const f32x4*)(eb + row * 68 + cb + q * 8 + 4);
        const size_t g8 = gb + q * 8;
        const f16x8 yh8 = *(const f16x8*)(yhP + g8);
        const f16x8 hh8 = *(const f16x8*)(hhP + g8);
        const f32x4 xt0 = *(const f32x4*)(xtw + g8);
        const f32x4 xt1 = *(const f32x4*)(xtw + g8 + 4);
        f16x8 oh, oy;
#pragma unroll
        for (int j = 0; j < 8; ++j) {
            const float av = (j < 4) ? a0[j] : a1[j - 4];
            const float xv = (j < 4) ? xt0[j] : xt1[j - 4];
            const float yv = (float)yh8[j];
            const float hv = (float)hh8[j];
            const float t1 = fmaf(invL, xv, yv);
            const float hn = fmaxf(fmaf(-invLs, av, t1), 0.f);
            const float yn = fmaf(cm, hn - hv, hn);
            oh[j] = (f16)hn;
            oy[j] = (f16)yn;
        }
        *(f16x8*)(HO + g8) = oh;
        *(f16x8*)(YO + g8) = oy;
    }
}

// ---------------------------------------------------------------------------
// Power iteration (deterministic, no atomics): wout = WtW @ (win/||win||)
// ---------------------------------------------------------------------------
__global__ void initw_kernel(float* __restrict__ w)
{
    w[threadIdx.x] = 0.03125f;               // 1/sqrt(1024), ||w||=1 exactly
}

__global__ __launch_bounds__(256) void matvec_n_kernel(const float* __restrict__ WtW,
                                                       const float* __restrict__ win,
                                                       float* __restrict__ wout)
{
    __shared__ float red[4];
    __shared__ float invnS;
    const int t = threadIdx.x;
    const int wave = t >> 6, lane = t & 63;

    const float4 wv = *(const float4*)(win + t * 4);
    float ss = wv.x * wv.x + wv.y * wv.y + wv.z * wv.z + wv.w * wv.w;
#pragma unroll
    for (int off = 32; off > 0; off >>= 1) ss += __shfl_down(ss, off);
    if (lane == 0) red[wave] = ss;
    __syncthreads();
    if (t == 0) invnS = 1.0f / (sqrtf(red[0] + red[1] + red[2] + red[3]) + 1e-12f);
    __syncthreads();
    const float invn = invnS;

    const int row = blockIdx.x * 4 + wave;
    const float* rp = WtW + (size_t)row * KD;
    float s = 0.f;
#pragma unroll
    for (int q = 0; q < KD / 64; ++q)
        s = fmaf(rp[lane + 64 * q], win[lane + 64 * q] * invn, s);
#pragma unroll
    for (int off = 32; off > 0; off >>= 1) s += __shfl_down(s, off);
    if (lane == 0) wout[row] = s;
}

__global__ __launch_bounds__(1024) void rayleigh_n_kernel(const float* __restrict__ w30,
                                                          const float* __restrict__ u31,
                                                          float* __restrict__ invL)
{
    __shared__ float red[16];
    __shared__ float invnS;
    const int t = threadIdx.x;
    const float a = w30[t];
    float ss = a * a;
#pragma unroll
    for (int off = 32; off > 0; off >>= 1) ss += __shfl_down(ss, off);
    if ((t & 63) == 0) red[t >> 6] = ss;
    __syncthreads();
    if (t < 64) {
        float v = (t < 16) ? red[t] : 0.f;
#pragma unroll
        for (int off = 8; off > 0; off >>= 1) v += __shfl_down(v, off);
        if (t == 0) invnS = 1.0f / (sqrtf(v) + 1e-12f);
    }
    __syncthreads();
    float s = (a * invnS) * u31[t];
#pragma unroll
    for (int off = 32; off > 0; off >>= 1) s += __shfl_down(s, off);
    __syncthreads();
    if ((t & 63) == 0) red[t >> 6] = s;
    __syncthreads();
    if (t == 0) {
        float tot = 0.f;
#pragma unroll
        for (int i = 0; i < 16; ++i) tot += red[i];
        invL[0] = 1.0f / tot;
    }
}

// ---------------------------------------------------------------------------
// out[i][b] = sum_j Wy[i][j] * H[b][j]   (out: [YD x BATCH])
// ---------------------------------------------------------------------------
__global__ __launch_bounds__(256) void ypred_kernel(const float* __restrict__ Wy,
                                                    const f16* __restrict__ hh,
                                                    float* __restrict__ out)
{
    const int wave = threadIdx.x >> 6;
    const int lane = threadIdx.x & 63;
    const int b    = blockIdx.x * 4 + wave;
    float p[YD] = {};
    const f16* hp = hh + (size_t)b * KD;
#pragma unroll 4
    for (int q = 0; q < KD / 64; ++q) {
        const int j = lane + 64 * q;
        const float hv = (float)hp[j];
#pragma unroll
        for (int i = 0; i < YD; ++i)
            p[i] = fmaf(Wy[i * KD + j], hv, p[i]);
    }
#pragma unroll
    for (int i = 0; i < YD; ++i) {
        float s = p[i];
#pragma unroll
        for (int off = 32; off > 0; off >>= 1)
            s += __shfl_down(s, off);
        if (lane == 0) out[(size_t)i * BATCH + b] = s;
    }
}

// ---------------------------------------------------------------------------
extern "C" void kernel_launch(void* const* d_in, const int* in_sizes, int n_in,
                              void* d_out, int out_size, void* d_ws, size_t ws_size,
                              hipStream_t stream)
{
    const float* x      = (const float*)d_in[0];   // [784 x 2048]
    const float* Wx     = (const float*)d_in[1];   // [784 x 1024]
    const float* Wy     = (const float*)d_in[2];   // [10 x 1024]
    const float* h_init = (const float*)d_in[3];   // [2048 x 1024]
    float* out = (float*)d_out;                    // [10 x 2048]

    char* base = (char*)d_ws;
    const size_t MB = 1 << 20;
    float* WtW  = (float*)(base + 0 * MB);         // 4 MB
    float* XtW  = (float*)(base + 4 * MB);         // 8 MB
    f16* bhiP   = (f16*)(base + 12 * MB);          // 2 MB
    f16* bloP   = (f16*)(base + 14 * MB);          // 2 MB
    f16* h0f    = (f16*)(base + 16 * MB);          // 4 MB
    f16* hA     = (f16*)(base + 20 * MB);
    f16* yA     = (f16*)(base + 24 * MB);
    f16* hB     = (f16*)(base + 28 * MB);
    f16* yB     = (f16*)(base + 32 * MB);
    float* wA   = (float*)(base + 36 * MB);
    float* wB   = (float*)(base + 36 * MB + 8192);
    float* invL = (float*)(base + 36 * MB + 16384);

    // 1) WtW = Wx^T Wx ; XtW = x^T Wx
    atb_kernel<<<dim3(KD / TS, KD / TS), 256, 0, stream>>>(Wx, Wx, WtW, KD, KD, XD);
    atb_kernel<<<dim3(KD / TS, BATCH / TS), 256, 0, stream>>>(x, Wx, XtW, BATCH, KD, XD);

    // 2) split 256*WtW into f16 hi/lo planes; h_init -> f16
    split_kernel<<<(KD * KD / 4 + 255) / 256, 256, 0, stream>>>(WtW, bhiP, bloP, 256.0f, KD * KD / 4);
    tof16_kernel<<<(BATCH * KD / 8 + 255) / 256, 256, 0, stream>>>(h_init, h0f, BATCH * KD / 8);

    // 3) Lipschitz: 31 fused norm+matvec launches, then Rayleigh
    //    writes: it=0 -> wB(u1), ..., it=29 -> wB(u30), it=30 -> wA(u31)
    initw_kernel<<<1, 1024, 0, stream>>>(wA);
    float* wcur = wA; float* wnxt = wB;
    for (int it = 0; it < 31; ++it) {
        matvec_n_kernel<<<KD / 4, 256, 0, stream>>>(WtW, wcur, wnxt);
        float* tmp = wcur; wcur = wnxt; wnxt = tmp;
    }
    rayleigh_n_kernel<<<1, 1024, 0, stream>>>(wB, wA, invL);

    // 4) 60 FISTA iterations (t restarts at iter 50: y = h, t = 1)
    float t = 1.0f;
    const f16 *yin = h0f, *hin = h0f;
    int outSel = 1;                                 // 1 -> A set, 0 -> B set
    for (int n = 0; n < 60; ++n) {
        if (n == 50) { t = 1.0f; yin = hin; }
        const float tn = 0.5f * (1.0f + sqrtf(1.0f + 4.0f * t * t));
        const float cm = (t - 1.0f) / tn;
        f16* ho = outSel ? hA : hB;
        f16* yo = outSel ? yA : yB;
        fista2<<<dim3(KD / BNF, BATCH / BMF), 256, 0, stream>>>(
            yin, hin, bhiP, bloP, XtW, invL, cm, ho, yo);
        t = tn;
        hin = ho; yin = yo;
        outSel ^= 1;
    }

    // 5) out = Wy @ h^T
    ypred_kernel<<<BATCH / 4, 256, 0, stream>>>(Wy, hin, out);
}